// Round 3
// baseline (322.105 us; speedup 1.0000x reference)
//
#include <hip/hip_runtime.h>

// Problem constants: B=1, C=32, H=96, W=192, max_disp=192 → D=64
// Output: (1, 2C, D, H, W) fp32, 302 MB.
//   ch <  C : out = x[ch][h][w]      * (w >= d)
//   ch >= C : out = y[ch-C][h][w-d]  * (w >= d)
//
// R2 rewrite: LINEAR streaming store order. The harness's fillBufferAligned
// sustains ~6.0 TB/s on this exact buffer with a linear dwordx4 stream; our
// previous d-plane-strided pattern (72 KB stride per thread-iteration) ran at
// ~2.9 TB/s. This version walks the output in ascending address order
// (grid-stride over float4s, consecutive lanes → consecutive 16B) and derives
// (ch,d,h,w) from the linear index. d and ch are wave-uniform because a
// (ch,d)-plane is 4608 float4s (multiple of 64).
constexpr int C      = 32;
constexpr int D      = 64;                 // max_disp / 3
constexpr int H      = 96;
constexpr int W      = 192;
constexpr int PLANE4 = H * W / 4;          // 4608 float4s per (ch,d) plane
constexpr int TOTAL4 = 2 * C * D * PLANE4; // 18,874,368 float4s

typedef float f4  __attribute__((ext_vector_type(4)));
typedef float f4u __attribute__((ext_vector_type(4), aligned(4))); // 4B-aligned vec load (global_load_dwordx4 needs only dword align)

__global__ __launch_bounds__(256) void fusion_kernel(const float* __restrict__ x,
                                                     const float* __restrict__ y,
                                                     float* __restrict__ out) {
    const int nthreads = gridDim.x * blockDim.x;   // 1,179,648 → 16 iterations
    int o4 = blockIdx.x * blockDim.x + threadIdx.x;
    #pragma unroll 2
    for (; o4 < TOTAL4; o4 += nthreads) {
        const int chd = o4 / PLANE4;        // ch*D + d   (wave-uniform)
        const int rem = o4 - chd * PLANE4;  // h*48 + w4  (lane-consecutive)
        const int ch  = chd >> 6;           // D = 64
        const int d   = chd & 63;
        const int w   = (rem % 48) * 4;     // within-row w of component 0

        f4 v;
        if (ch < C) {
            // x[ch][h][w..w+3] — aligned vec4, L2-resident (x = 2.36 MB)
            v = *(const f4*)(x + ch * (H * W) + rem * 4);
        } else {
            // y[ch-C][h][w-d .. w+3-d]: within-plane offset rem*4 - d.
            // Row-underflow lanes are masked below; only guard y[0].
            const int off = (ch - C) * (H * W) + rem * 4 - d;
            if (off >= 0) {
                v = *(const f4u*)(y + off); // unaligned-capable dwordx4
            } else {
                // only first waves of ch'=0 planes hit this (rare, masked comps)
                v.x = y[max(off + 0, 0)];
                v.y = y[max(off + 1, 0)];
                v.z = y[max(off + 2, 0)];
                v.w = y[max(off + 3, 0)];
            }
        }
        if (w < d) {                        // d uniform, w lane-varying
            if (w + 0 < d) v.x = 0.f;
            if (w + 1 < d) v.y = 0.f;
            if (w + 2 < d) v.z = 0.f;
            if (w + 3 < d) v.w = 0.f;
        }
        *(f4*)(out + (long long)o4 * 4) = v; // linear 1 KB per wave-store
    }
}

extern "C" void kernel_launch(void* const* d_in, const int* in_sizes, int n_in,
                              void* d_out, int out_size, void* d_ws, size_t ws_size,
                              hipStream_t stream) {
    const float* x = (const float*)d_in[0];
    const float* y = (const float*)d_in[1];
    float* out     = (float*)d_out;

    constexpr int block = 256;
    constexpr int grid  = 4608;            // 18 blocks/CU; 16 f4-iterations/thread
    fusion_kernel<<<grid, block, 0, stream>>>(x, y, out);
}